// Round 2
// baseline (4805.008 us; speedup 1.0000x reference)
//
#include <hip/hip_runtime.h>

#define D_FEAT 128
#define BM 128
#define BN 128
#define BK 32

// Order-preserving float<->uint mapping so float-max can use atomicMax(uint).
// encode(f) > 0 for every real float (min real: -FLT_MAX -> 0x00800000),
// so 0u is a safe "segment empty" sentinel (and memset(0)-compatible).
__device__ __forceinline__ unsigned int fenc(float f) {
    unsigned int u = __float_as_uint(f);
    return (u & 0x80000000u) ? ~u : (u | 0x80000000u);
}
__device__ __forceinline__ float fdec(unsigned int u) {
    u = (u & 0x80000000u) ? (u & 0x7FFFFFFFu) : ~u;
    return __uint_as_float(u);
}

// W [128 out][256 in] row-major -> Wt [256 k][128 n] so GEMM B-tile loads coalesce.
__global__ __launch_bounds__(256) void wt_kernel(const float* __restrict__ W,
                                                 float* __restrict__ Wt) {
    int i = blockIdx.x * 256 + threadIdx.x;   // 0 .. 32767
    int k = i >> 7;
    int d = i & (D_FEAT - 1);
    Wt[i] = W[(size_t)d * (2 * D_FEAT) + k];
}

// One thread per (edge, 4-feature group): float4 load of src, 4 atomicAdd + 4 atomicMax.
__global__ __launch_bounds__(256) void scatter_kernel(
    const float* __restrict__ src, const int* __restrict__ index,
    float* __restrict__ s_add, unsigned int* __restrict__ s_max, int n_edges)
{
    int i = blockIdx.x * 256 + threadIdx.x;
    int total = n_edges * (D_FEAT / 4);
    if (i >= total) return;
    int e  = i >> 5;          // edge
    int d4 = (i & 31) << 2;   // feature offset (0,4,...,124)
    int seg = index[e];
    const float4 v = *reinterpret_cast<const float4*>(src + (size_t)e * D_FEAT + d4);
    float*        ap = s_add + (size_t)seg * D_FEAT + d4;
    unsigned int* mp = s_max + (size_t)seg * D_FEAT + d4;
    atomicAdd(ap + 0, v.x);
    atomicAdd(ap + 1, v.y);
    atomicAdd(ap + 2, v.z);
    atomicAdd(ap + 3, v.w);
    atomicMax(mp + 0, fenc(v.x));
    atomicMax(mp + 1, fenc(v.y));
    atomicMax(mp + 2, fenc(v.z));
    atomicMax(mp + 3, fenc(v.w));
}

// C[M,128] = A[M,256] * Wt[256,128] + bias, where A[:, :128] = s_add and
// A[:, 128:] = decode(s_max) (sentinel 0 -> 0.0f, matching torch_scatter).
__global__ __launch_bounds__(256) void gemm_kernel(
    const float* __restrict__ s_add, const unsigned int* __restrict__ s_max,
    const float* __restrict__ Wt, const float* __restrict__ bias,
    float* __restrict__ out, int M)
{
    __shared__ float As[BK][BM + 4];   // k-major, padded
    __shared__ float Bs[BK][BN];

    const int t = threadIdx.x;
    const int m_base = blockIdx.x * BM;
    const int ty = t >> 4, tx = t & 15;
    const int trow = ty * 8, tcol = tx * 8;

    float acc[8][8] = {};

    for (int k0 = 0; k0 < 2 * D_FEAT; k0 += BK) {
        const bool hi = (k0 >= D_FEAT);
        const int kk = hi ? (k0 - D_FEAT) : k0;

        // stage A tile [BM rows][BK k], transposed into As[k][m]
        #pragma unroll
        for (int p = 0; p < 4; ++p) {
            int m  = p * 32 + (t >> 3);      // 0..127
            int kv = (t & 7) << 2;           // 0,4,...,28
            int gm = m_base + m;
            float4 v = make_float4(0.f, 0.f, 0.f, 0.f);
            if (gm < M) {
                if (!hi) {
                    v = *reinterpret_cast<const float4*>(s_add + (size_t)gm * D_FEAT + kk + kv);
                } else {
                    uint4 u = *reinterpret_cast<const uint4*>(s_max + (size_t)gm * D_FEAT + kk + kv);
                    v.x = u.x ? fdec(u.x) : 0.f;
                    v.y = u.y ? fdec(u.y) : 0.f;
                    v.z = u.z ? fdec(u.z) : 0.f;
                    v.w = u.w ? fdec(u.w) : 0.f;
                }
            }
            As[kv + 0][m] = v.x;
            As[kv + 1][m] = v.y;
            As[kv + 2][m] = v.z;
            As[kv + 3][m] = v.w;
        }
        // stage B tile [BK][BN] from pre-transposed Wt (coalesced)
        #pragma unroll
        for (int p = 0; p < 4; ++p) {
            int k  = p * 8 + (t >> 5);       // 0..31
            int nv = (t & 31) << 2;          // 0..124
            *reinterpret_cast<float4*>(&Bs[k][nv]) =
                *reinterpret_cast<const float4*>(Wt + (size_t)(k0 + k) * BN + nv);
        }
        __syncthreads();

        #pragma unroll
        for (int k = 0; k < BK; ++k) {
            float a[8], b[8];
            #pragma unroll
            for (int i = 0; i < 8; ++i) a[i] = As[k][trow + i];
            #pragma unroll
            for (int j = 0; j < 8; ++j) b[j] = Bs[k][tcol + j];
            #pragma unroll
            for (int i = 0; i < 8; ++i)
                #pragma unroll
                for (int j = 0; j < 8; ++j)
                    acc[i][j] += a[i] * b[j];
        }
        __syncthreads();
    }

    // epilogue: add bias, store
    #pragma unroll
    for (int i = 0; i < 8; ++i) {
        int gm = m_base + trow + i;
        if (gm >= M) continue;
        #pragma unroll
        for (int j = 0; j < 8; j += 4) {
            float4 r;
            r.x = acc[i][j + 0] + bias[tcol + j + 0];
            r.y = acc[i][j + 1] + bias[tcol + j + 1];
            r.z = acc[i][j + 2] + bias[tcol + j + 2];
            r.w = acc[i][j + 3] + bias[tcol + j + 3];
            *reinterpret_cast<float4*>(out + (size_t)gm * BN + tcol + j) = r;
        }
    }
}

extern "C" void kernel_launch(void* const* d_in, const int* in_sizes, int n_in,
                              void* d_out, int out_size, void* d_ws, size_t ws_size,
                              hipStream_t stream) {
    const float* src   = (const float*)d_in[0];
    const int*   index = (const int*)d_in[1];
    const float* W     = (const float*)d_in[2];
    const float* bias  = (const float*)d_in[3];

    const int n_edges = in_sizes[0] / D_FEAT;   // 1,600,000
    const int M       = out_size / D_FEAT;      // 50,000 (dim_size)

    // workspace layout: s_add [M*128 f32] | s_max [M*128 u32] | Wt [256*128 f32]
    float*        s_add = (float*)d_ws;
    unsigned int* s_max = (unsigned int*)(s_add + (size_t)M * D_FEAT);
    float*        Wt    = (float*)(s_max + (size_t)M * D_FEAT);

    // zero-init: 0.0f for sums, 0u sentinel (= "empty") for encoded maxes
    hipMemsetAsync(d_ws, 0, (size_t)M * D_FEAT * 8, stream);

    wt_kernel<<<(2 * D_FEAT * D_FEAT + 255) / 256, 256, 0, stream>>>(W, Wt);

    int total = n_edges * (D_FEAT / 4);
    scatter_kernel<<<(total + 255) / 256, 256, 0, stream>>>(src, index, s_add, s_max, n_edges);

    gemm_kernel<<<(M + BM - 1) / BM, 256, 0, stream>>>(s_add, s_max, Wt, bias,
                                                       (float*)d_out, M);
}

// Round 3
// 588.090 us; speedup vs baseline: 8.1705x; 8.1705x over previous
//
#include <hip/hip_runtime.h>
#include <math.h>

#define D_FEAT 128
#define BM 128
#define BN 128
#define BK 32

// W [128 out][256 in] row-major -> Wt [256 k][128 n] so GEMM B-tile loads coalesce.
__global__ __launch_bounds__(256) void wt_kernel(const float* __restrict__ W,
                                                 float* __restrict__ Wt) {
    int i = blockIdx.x * 256 + threadIdx.x;   // 0 .. 32767
    int k = i >> 7;
    int d = i & (D_FEAT - 1);
    Wt[i] = W[(size_t)d * (2 * D_FEAT) + k];
}

// 1) histogram of segment ids
__global__ __launch_bounds__(256) void hist_kernel(const int* __restrict__ index,
                                                   int* __restrict__ cnt, int n) {
    int i = blockIdx.x * 256 + threadIdx.x;
    if (i < n) atomicAdd(&cnt[index[i]], 1);
}

// 2) exclusive scan over n counters -> off[0..n] ; also copy to cursor[0..n-1].
//    Single 1024-thread block: per-thread chunk totals -> LDS scan -> write pass.
__global__ __launch_bounds__(1024) void scan_kernel(const int* __restrict__ cnt,
                                                    int* __restrict__ off,
                                                    int* __restrict__ cursor, int n) {
    __shared__ int sh[1024];
    const int t = threadIdx.x;
    const int items = (n + 1 + 1023) / 1024;
    const int lo = t * items;
    const int hi = min(lo + items, n + 1);

    int total = 0;
    for (int i = lo; i < hi; ++i) total += (i < n) ? cnt[i] : 0;

    sh[t] = total;
    __syncthreads();
    for (int s = 1; s < 1024; s <<= 1) {
        int v = (t >= s) ? sh[t - s] : 0;
        __syncthreads();
        sh[t] += v;
        __syncthreads();
    }
    int run = sh[t] - total;   // exclusive prefix of this thread's chunk

    for (int i = lo; i < hi; ++i) {
        off[i] = run;
        if (i < n) {
            cursor[i] = run;
            run += cnt[i];
        }
    }
}

// 3) scatter edge ids into segment-sorted order
__global__ __launch_bounds__(256) void order_kernel(const int* __restrict__ index,
                                                    int* __restrict__ cursor,
                                                    int* __restrict__ order, int n) {
    int i = blockIdx.x * 256 + threadIdx.x;
    if (i < n) {
        int pos = atomicAdd(&cursor[index[i]], 1);
        order[pos] = i;
    }
}

// 4) one wave per segment: register-resident sum+max over the segment's edges.
//    lane owns features {2*lane, 2*lane+1}; writes A[seg][0:128]=sum, A[seg][128:256]=max.
__global__ __launch_bounds__(256) void reduce_kernel(
    const float* __restrict__ src, const int* __restrict__ order,
    const int* __restrict__ off, float* __restrict__ A, int nseg)
{
    int wid  = (blockIdx.x * 256 + threadIdx.x) >> 6;
    int lane = threadIdx.x & 63;
    if (wid >= nseg) return;

    const int start = off[wid], end = off[wid + 1];

    float2 sA = make_float2(0.f, 0.f), sB = make_float2(0.f, 0.f);
    float2 mA = make_float2(-INFINITY, -INFINITY), mB = mA;

    int p = start;
    for (; p + 1 < end; p += 2) {
        int e0 = order[p], e1 = order[p + 1];
        float2 a0 = *reinterpret_cast<const float2*>(src + (size_t)e0 * D_FEAT + 2 * lane);
        float2 a1 = *reinterpret_cast<const float2*>(src + (size_t)e1 * D_FEAT + 2 * lane);
        sA.x += a0.x; sA.y += a0.y;
        sB.x += a1.x; sB.y += a1.y;
        mA.x = fmaxf(mA.x, a0.x); mA.y = fmaxf(mA.y, a0.y);
        mB.x = fmaxf(mB.x, a1.x); mB.y = fmaxf(mB.y, a1.y);
    }
    if (p < end) {
        int e0 = order[p];
        float2 a0 = *reinterpret_cast<const float2*>(src + (size_t)e0 * D_FEAT + 2 * lane);
        sA.x += a0.x; sA.y += a0.y;
        mA.x = fmaxf(mA.x, a0.x); mA.y = fmaxf(mA.y, a0.y);
    }

    float2 sum = make_float2(sA.x + sB.x, sA.y + sB.y);
    float2 mx;
    if (end > start) {
        mx = make_float2(fmaxf(mA.x, mB.x), fmaxf(mA.y, mB.y));
    } else {
        mx = make_float2(0.f, 0.f);   // torch_scatter: empty segment max -> 0
    }

    float* row = A + (size_t)wid * (2 * D_FEAT);
    *reinterpret_cast<float2*>(row + 2 * lane)          = sum;
    *reinterpret_cast<float2*>(row + D_FEAT + 2 * lane) = mx;
}

// 5) out[M,128] = A[M,256] * Wt[256,128] + bias
__global__ __launch_bounds__(256) void gemm_kernel(
    const float* __restrict__ A, const float* __restrict__ Wt,
    const float* __restrict__ bias, float* __restrict__ out, int M)
{
    __shared__ float As[BK][BM + 4];   // k-major, padded
    __shared__ float Bs[BK][BN];

    const int t = threadIdx.x;
    const int m_base = blockIdx.x * BM;
    const int ty = t >> 4, tx = t & 15;
    const int trow = ty * 8, tcol = tx * 8;

    float acc[8][8] = {};

    for (int k0 = 0; k0 < 2 * D_FEAT; k0 += BK) {
        // stage A tile [BM rows][BK k], transposed into As[k][m]
        #pragma unroll
        for (int p = 0; p < 4; ++p) {
            int m  = p * 32 + (t >> 3);      // 0..127
            int kv = (t & 7) << 2;           // 0,4,...,28
            int gm = m_base + m;
            float4 v = make_float4(0.f, 0.f, 0.f, 0.f);
            if (gm < M)
                v = *reinterpret_cast<const float4*>(A + (size_t)gm * (2 * D_FEAT) + k0 + kv);
            As[kv + 0][m] = v.x;
            As[kv + 1][m] = v.y;
            As[kv + 2][m] = v.z;
            As[kv + 3][m] = v.w;
        }
        // stage B tile [BK][BN] from pre-transposed Wt (coalesced)
        #pragma unroll
        for (int p = 0; p < 4; ++p) {
            int k  = p * 8 + (t >> 5);       // 0..31
            int nv = (t & 31) << 2;          // 0..124
            *reinterpret_cast<float4*>(&Bs[k][nv]) =
                *reinterpret_cast<const float4*>(Wt + (size_t)(k0 + k) * BN + nv);
        }
        __syncthreads();

        #pragma unroll
        for (int k = 0; k < BK; ++k) {
            float a[8], b[8];
            #pragma unroll
            for (int i = 0; i < 8; ++i) a[i] = As[k][trow + i];
            #pragma unroll
            for (int j = 0; j < 8; ++j) b[j] = Bs[k][tcol + j];
            #pragma unroll
            for (int i = 0; i < 8; ++i)
                #pragma unroll
                for (int j = 0; j < 8; ++j)
                    acc[i][j] += a[i] * b[j];
        }
        __syncthreads();
    }

    #pragma unroll
    for (int i = 0; i < 8; ++i) {
        int gm = m_base + trow + i;
        if (gm >= M) continue;
        #pragma unroll
        for (int j = 0; j < 8; j += 4) {
            float4 r;
            r.x = acc[i][j + 0] + bias[tcol + j + 0];
            r.y = acc[i][j + 1] + bias[tcol + j + 1];
            r.z = acc[i][j + 2] + bias[tcol + j + 2];
            r.w = acc[i][j + 3] + bias[tcol + j + 3];
            *reinterpret_cast<float4*>(out + (size_t)gm * BN + tcol + j) = r;
        }
    }
}

extern "C" void kernel_launch(void* const* d_in, const int* in_sizes, int n_in,
                              void* d_out, int out_size, void* d_ws, size_t ws_size,
                              hipStream_t stream) {
    const float* src   = (const float*)d_in[0];
    const int*   index = (const int*)d_in[1];
    const float* W     = (const float*)d_in[2];
    const float* bias  = (const float*)d_in[3];

    const int n_edges = in_sizes[1];            // 1,600,000
    const int M       = out_size / D_FEAT;      // 50,000 (dim_size)

    // workspace layout
    float* A      = (float*)d_ws;                    // M * 256 f32
    float* Wt     = A + (size_t)M * 2 * D_FEAT;      // 256*128 f32
    int*   cnt    = (int*)(Wt + 2 * D_FEAT * D_FEAT);// M
    int*   off    = cnt + M;                         // M + 1
    int*   cursor = off + M + 1;                     // M
    int*   order  = cursor + M;                      // n_edges

    hipMemsetAsync(cnt, 0, (size_t)M * sizeof(int), stream);

    wt_kernel<<<(2 * D_FEAT * D_FEAT + 255) / 256, 256, 0, stream>>>(W, Wt);

    int eb = (n_edges + 255) / 256;
    hist_kernel<<<eb, 256, 0, stream>>>(index, cnt, n_edges);
    scan_kernel<<<1, 1024, 0, stream>>>(cnt, off, cursor, M);
    order_kernel<<<eb, 256, 0, stream>>>(index, cursor, order, n_edges);

    int rb = (M * 64 + 255) / 256;
    reduce_kernel<<<rb, 256, 0, stream>>>(src, order, off, A, M);

    gemm_kernel<<<(M + BM - 1) / BM, 256, 0, stream>>>(A, Wt, bias, (float*)d_out, M);
}

// Round 4
// 586.870 us; speedup vs baseline: 8.1875x; 1.0021x over previous
//
#include <hip/hip_runtime.h>
#include <math.h>

#define D_FEAT 128
#define BM 128
#define BN 128
#define BK 32

// zero the histogram counters (avoid hipMemsetAsync graph node)
__global__ __launch_bounds__(256) void zero_kernel(int* __restrict__ p, int n) {
    int i = blockIdx.x * 256 + threadIdx.x;
    if (i < n) p[i] = 0;
}

// W [128 out][256 in] row-major -> Wt [256 k][128 n] so GEMM B-tile loads coalesce.
__global__ __launch_bounds__(256) void wt_kernel(const float* __restrict__ W,
                                                 float* __restrict__ Wt) {
    int i = blockIdx.x * 256 + threadIdx.x;   // 0 .. 32767
    int k = i >> 7;
    int d = i & (D_FEAT - 1);
    Wt[i] = W[(size_t)d * (2 * D_FEAT) + k];
}

// 1) histogram of segment ids
__global__ __launch_bounds__(256) void hist_kernel(const int* __restrict__ index,
                                                   int* __restrict__ cnt, int n) {
    int i = blockIdx.x * 256 + threadIdx.x;
    if (i < n) atomicAdd(&cnt[index[i]], 1);
}

// 2) exclusive scan over n counters -> off[0..n] ; also copy to cursor[0..n-1].
__global__ __launch_bounds__(1024) void scan_kernel(const int* __restrict__ cnt,
                                                    int* __restrict__ off,
                                                    int* __restrict__ cursor, int n) {
    __shared__ int sh[1024];
    const int t = threadIdx.x;
    const int items = (n + 1 + 1023) / 1024;
    const int lo = t * items;
    const int hi = min(lo + items, n + 1);

    int total = 0;
    for (int i = lo; i < hi; ++i) total += (i < n) ? cnt[i] : 0;

    sh[t] = total;
    __syncthreads();
    for (int s = 1; s < 1024; s <<= 1) {
        int v = (t >= s) ? sh[t - s] : 0;
        __syncthreads();
        sh[t] += v;
        __syncthreads();
    }
    int run = sh[t] - total;   // exclusive prefix of this thread's chunk

    for (int i = lo; i < hi; ++i) {
        off[i] = run;
        if (i < n) {
            cursor[i] = run;
            run += cnt[i];
        }
    }
}

// 3) scatter edge ids into segment-sorted order
__global__ __launch_bounds__(256) void order_kernel(const int* __restrict__ index,
                                                    int* __restrict__ cursor,
                                                    int* __restrict__ order, int n) {
    int i = blockIdx.x * 256 + threadIdx.x;
    if (i < n) {
        int pos = atomicAdd(&cursor[index[i]], 1);
        order[pos] = i;
    }
}

// 4) one wave per segment, split into two 32-lane halves (even/odd edges).
//    lane handles features [4*(lane&31), +4) via float4; halves combined with
//    one shfl_xor(32); half 0 writes the sum row, half 1 the max row.
__global__ __launch_bounds__(256) void reduce_kernel(
    const float* __restrict__ src, const int* __restrict__ order,
    const int* __restrict__ off, float* __restrict__ A, int nseg)
{
    int wid  = (blockIdx.x * 256 + threadIdx.x) >> 6;
    int lane = threadIdx.x & 63;
    if (wid >= nseg) return;
    const int half = lane >> 5;
    const int fl   = (lane & 31) << 2;   // feature offset 0..124

    const int start = off[wid], end = off[wid + 1];

    float4 s = make_float4(0.f, 0.f, 0.f, 0.f);
    float4 m = make_float4(-INFINITY, -INFINITY, -INFINITY, -INFINITY);

    #pragma unroll 2
    for (int p = start + half; p < end; p += 2) {
        int e = order[p];
        float4 v = *reinterpret_cast<const float4*>(src + (size_t)e * D_FEAT + fl);
        s.x += v.x; s.y += v.y; s.z += v.z; s.w += v.w;
        m.x = fmaxf(m.x, v.x); m.y = fmaxf(m.y, v.y);
        m.z = fmaxf(m.z, v.z); m.w = fmaxf(m.w, v.w);
    }

    // combine the two halves
    s.x += __shfl_xor(s.x, 32); s.y += __shfl_xor(s.y, 32);
    s.z += __shfl_xor(s.z, 32); s.w += __shfl_xor(s.w, 32);
    m.x = fmaxf(m.x, __shfl_xor(m.x, 32)); m.y = fmaxf(m.y, __shfl_xor(m.y, 32));
    m.z = fmaxf(m.z, __shfl_xor(m.z, 32)); m.w = fmaxf(m.w, __shfl_xor(m.w, 32));

    if (end == start) m = make_float4(0.f, 0.f, 0.f, 0.f);  // torch_scatter empty -> 0

    float* row = A + (size_t)wid * (2 * D_FEAT);
    if (half == 0) *reinterpret_cast<float4*>(row + fl)          = s;
    else           *reinterpret_cast<float4*>(row + D_FEAT + fl) = m;
}

// 5) out[M,128] = A[M,256] * Wt[256,128] + bias
__global__ __launch_bounds__(256) void gemm_kernel(
    const float* __restrict__ A, const float* __restrict__ Wt,
    const float* __restrict__ bias, float* __restrict__ out, int M)
{
    __shared__ float As[BK][BM + 4];   // k-major, padded
    __shared__ float Bs[BK][BN];

    const int t = threadIdx.x;
    const int m_base = blockIdx.x * BM;
    const int ty = t >> 4, tx = t & 15;
    const int trow = ty * 8, tcol = tx * 8;

    float acc[8][8] = {};

    for (int k0 = 0; k0 < 2 * D_FEAT; k0 += BK) {
        #pragma unroll
        for (int p = 0; p < 4; ++p) {
            int m  = p * 32 + (t >> 3);
            int kv = (t & 7) << 2;
            int gm = m_base + m;
            float4 v = make_float4(0.f, 0.f, 0.f, 0.f);
            if (gm < M)
                v = *reinterpret_cast<const float4*>(A + (size_t)gm * (2 * D_FEAT) + k0 + kv);
            As[kv + 0][m] = v.x;
            As[kv + 1][m] = v.y;
            As[kv + 2][m] = v.z;
            As[kv + 3][m] = v.w;
        }
        #pragma unroll
        for (int p = 0; p < 4; ++p) {
            int k  = p * 8 + (t >> 5);
            int nv = (t & 31) << 2;
            *reinterpret_cast<float4*>(&Bs[k][nv]) =
                *reinterpret_cast<const float4*>(Wt + (size_t)(k0 + k) * BN + nv);
        }
        __syncthreads();

        #pragma unroll
        for (int k = 0; k < BK; ++k) {
            float a[8], b[8];
            #pragma unroll
            for (int i = 0; i < 8; ++i) a[i] = As[k][trow + i];
            #pragma unroll
            for (int j = 0; j < 8; ++j) b[j] = Bs[k][tcol + j];
            #pragma unroll
            for (int i = 0; i < 8; ++i)
                #pragma unroll
                for (int j = 0; j < 8; ++j)
                    acc[i][j] += a[i] * b[j];
        }
        __syncthreads();
    }

    #pragma unroll
    for (int i = 0; i < 8; ++i) {
        int gm = m_base + trow + i;
        if (gm >= M) continue;
        #pragma unroll
        for (int j = 0; j < 8; j += 4) {
            float4 r;
            r.x = acc[i][j + 0] + bias[tcol + j + 0];
            r.y = acc[i][j + 1] + bias[tcol + j + 1];
            r.z = acc[i][j + 2] + bias[tcol + j + 2];
            r.w = acc[i][j + 3] + bias[tcol + j + 3];
            *reinterpret_cast<float4*>(out + (size_t)gm * BN + tcol + j) = r;
        }
    }
}

extern "C" void kernel_launch(void* const* d_in, const int* in_sizes, int n_in,
                              void* d_out, int out_size, void* d_ws, size_t ws_size,
                              hipStream_t stream) {
    const float* src   = (const float*)d_in[0];
    const int*   index = (const int*)d_in[1];
    const float* W     = (const float*)d_in[2];
    const float* bias  = (const float*)d_in[3];

    const int n_edges = in_sizes[1];            // 1,600,000
    const int M       = out_size / D_FEAT;      // 50,000 (dim_size)

    // workspace layout
    float* A      = (float*)d_ws;                    // M * 256 f32
    float* Wt     = A + (size_t)M * 2 * D_FEAT;      // 256*128 f32
    int*   cnt    = (int*)(Wt + 2 * D_FEAT * D_FEAT);// M
    int*   off    = cnt + M;                         // M + 1
    int*   cursor = off + M + 1;                     // M
    int*   order  = cursor + M;                      // n_edges

    zero_kernel<<<(M + 255) / 256, 256, 0, stream>>>(cnt, M);

    wt_kernel<<<(2 * D_FEAT * D_FEAT + 255) / 256, 256, 0, stream>>>(W, Wt);

    int eb = (n_edges + 255) / 256;
    hist_kernel<<<eb, 256, 0, stream>>>(index, cnt, n_edges);
    scan_kernel<<<1, 1024, 0, stream>>>(cnt, off, cursor, M);
    order_kernel<<<eb, 256, 0, stream>>>(index, cursor, order, n_edges);

    int rb = (M * 64 + 255) / 256;
    reduce_kernel<<<rb, 256, 0, stream>>>(src, order, off, A, M);

    gemm_kernel<<<(M + BM - 1) / BM, 256, 0, stream>>>(A, Wt, bias, (float*)d_out, M);
}

// Round 5
// 444.793 us; speedup vs baseline: 10.8028x; 1.3194x over previous
//
#include <hip/hip_runtime.h>
#include <math.h>

#define D_FEAT 128
#define BM 128
#define BN 128
#define BK 32
#define SCAN_ITEMS 2048   // items per scan block (256 thr * 8)

// setup: zero histogram counters + transpose W -> Wt [256 k][128 n]
__global__ __launch_bounds__(256) void setup_kernel(const float* __restrict__ W,
                                                    float* __restrict__ Wt,
                                                    int* __restrict__ cnt, int M) {
    int i = blockIdx.x * 256 + threadIdx.x;
    if (i < 2 * D_FEAT * D_FEAT) {
        int k = i >> 7, d = i & (D_FEAT - 1);
        Wt[i] = W[(size_t)d * (2 * D_FEAT) + k];
    }
    if (i < M) cnt[i] = 0;
}

// 1) histogram of segment ids (int4 loads)
__global__ __launch_bounds__(256) void hist_kernel(const int* __restrict__ index,
                                                   int* __restrict__ cnt, int n4, int n) {
    int i = blockIdx.x * 256 + threadIdx.x;
    if (i < n4) {
        int4 v = reinterpret_cast<const int4*>(index)[i];
        atomicAdd(&cnt[v.x], 1);
        atomicAdd(&cnt[v.y], 1);
        atomicAdd(&cnt[v.z], 1);
        atomicAdd(&cnt[v.w], 1);
    }
    int rem = 4 * n4 + i;           // tail (none for n%4==0)
    if (i < n - 4 * n4) atomicAdd(&cnt[index[rem]], 1);
}

// 2a) per-block sums of cnt (coalesced)
__global__ __launch_bounds__(256) void blocksum_kernel(const int* __restrict__ cnt,
                                                       int* __restrict__ bsum, int n) {
    __shared__ int sh[256];
    const int b = blockIdx.x, t = threadIdx.x;
    const int base = b * SCAN_ITEMS;
    int s = 0;
    #pragma unroll
    for (int j = 0; j < 8; ++j) {
        int i = base + j * 256 + t;
        if (i < n) s += cnt[i];
    }
    sh[t] = s;
    __syncthreads();
    for (int st = 128; st > 0; st >>= 1) {
        if (t < st) sh[t] += sh[t + st];
        __syncthreads();
    }
    if (t == 0) bsum[b] = sh[0];
}

// 2b) single-wave scan of block sums (nblk <= 64); also writes off[n] = total
__global__ __launch_bounds__(64) void scanblk_kernel(const int* __restrict__ bsum,
                                                     int* __restrict__ boff,
                                                     int* __restrict__ off,
                                                     int n, int nblk) {
    int t = threadIdx.x;
    int v = (t < nblk) ? bsum[t] : 0;
    int orig = v;
    #pragma unroll
    for (int d = 1; d < 64; d <<= 1) {
        int u = __shfl_up(v, d);
        if (t >= d) v += u;
    }
    if (t < nblk) boff[t] = v - orig;   // exclusive
    if (t == 63) off[n] = v;            // grand total
}

// 2c) apply: per-block exclusive scan over its 2048 items -> off, cursor
__global__ __launch_bounds__(256) void apply_kernel(const int* __restrict__ cnt,
                                                    const int* __restrict__ boff,
                                                    int* __restrict__ off,
                                                    int* __restrict__ cursor, int n) {
    __shared__ int sh[SCAN_ITEMS];
    __shared__ int ts[256];
    const int b = blockIdx.x, t = threadIdx.x;
    const int base = b * SCAN_ITEMS;
    #pragma unroll
    for (int j = 0; j < 8; ++j) {
        int i = base + j * 256 + t;
        sh[j * 256 + t] = (i < n) ? cnt[i] : 0;
    }
    __syncthreads();
    int s = 0;
    #pragma unroll
    for (int j = 0; j < 8; ++j) s += sh[t * 8 + j];
    ts[t] = s;
    __syncthreads();
    for (int st = 1; st < 256; st <<= 1) {
        int u = (t >= st) ? ts[t - st] : 0;
        __syncthreads();
        ts[t] += u;
        __syncthreads();
    }
    int run = boff[b] + ts[t] - s;      // exclusive prefix for this thread's chunk
    #pragma unroll
    for (int j = 0; j < 8; ++j) {
        int i = base + t * 8 + j;
        if (i < n) {
            off[i] = run;
            cursor[i] = run;
            run += sh[t * 8 + j];
        }
    }
}

// 3) scatter edge ids into segment-sorted order (int4 loads)
__global__ __launch_bounds__(256) void order_kernel(const int* __restrict__ index,
                                                    int* __restrict__ cursor,
                                                    int* __restrict__ order, int n4, int n) {
    int i = blockIdx.x * 256 + threadIdx.x;
    if (i < n4) {
        int4 v = reinterpret_cast<const int4*>(index)[i];
        int e = 4 * i;
        order[atomicAdd(&cursor[v.x], 1)] = e;
        order[atomicAdd(&cursor[v.y], 1)] = e + 1;
        order[atomicAdd(&cursor[v.z], 1)] = e + 2;
        order[atomicAdd(&cursor[v.w], 1)] = e + 3;
    }
    int rem = 4 * n4 + i;
    if (i < n - 4 * n4) order[atomicAdd(&cursor[index[rem]], 1)] = rem;
}

// 4) one wave per segment, two 32-lane halves (even/odd edges), float4 per lane.
__global__ __launch_bounds__(256) void reduce_kernel(
    const float* __restrict__ src, const int* __restrict__ order,
    const int* __restrict__ off, float* __restrict__ A, int nseg)
{
    int wid  = (blockIdx.x * 256 + threadIdx.x) >> 6;
    int lane = threadIdx.x & 63;
    if (wid >= nseg) return;
    const int half = lane >> 5;
    const int fl   = (lane & 31) << 2;

    const int start = off[wid], end = off[wid + 1];

    float4 s = make_float4(0.f, 0.f, 0.f, 0.f);
    float4 m = make_float4(-INFINITY, -INFINITY, -INFINITY, -INFINITY);

    #pragma unroll 4
    for (int p = start + half; p < end; p += 2) {
        int e = order[p];
        float4 v = *reinterpret_cast<const float4*>(src + (size_t)e * D_FEAT + fl);
        s.x += v.x; s.y += v.y; s.z += v.z; s.w += v.w;
        m.x = fmaxf(m.x, v.x); m.y = fmaxf(m.y, v.y);
        m.z = fmaxf(m.z, v.z); m.w = fmaxf(m.w, v.w);
    }

    s.x += __shfl_xor(s.x, 32); s.y += __shfl_xor(s.y, 32);
    s.z += __shfl_xor(s.z, 32); s.w += __shfl_xor(s.w, 32);
    m.x = fmaxf(m.x, __shfl_xor(m.x, 32)); m.y = fmaxf(m.y, __shfl_xor(m.y, 32));
    m.z = fmaxf(m.z, __shfl_xor(m.z, 32)); m.w = fmaxf(m.w, __shfl_xor(m.w, 32));

    if (end == start) m = make_float4(0.f, 0.f, 0.f, 0.f);  // empty segment -> 0

    float* row = A + (size_t)wid * (2 * D_FEAT);
    if (half == 0) *reinterpret_cast<float4*>(row + fl)          = s;
    else           *reinterpret_cast<float4*>(row + D_FEAT + fl) = m;
}

// 5) out[M,128] = A[M,256] * Wt[256,128] + bias
__global__ __launch_bounds__(256) void gemm_kernel(
    const float* __restrict__ A, const float* __restrict__ Wt,
    const float* __restrict__ bias, float* __restrict__ out, int M)
{
    __shared__ float As[BK][BM + 4];   // row stride 132 floats (float4-aligned)
    __shared__ float Bs[BK][BN];

    const int t = threadIdx.x;
    const int m_base = blockIdx.x * BM;
    const int ty = t >> 4, tx = t & 15;
    const int trow = ty * 8, tcol = tx * 8;

    float acc[8][8] = {};

    for (int k0 = 0; k0 < 2 * D_FEAT; k0 += BK) {
        #pragma unroll
        for (int p = 0; p < 4; ++p) {
            int m  = p * 32 + (t >> 3);
            int kv = (t & 7) << 2;
            int gm = m_base + m;
            float4 v = make_float4(0.f, 0.f, 0.f, 0.f);
            if (gm < M)
                v = *reinterpret_cast<const float4*>(A + (size_t)gm * (2 * D_FEAT) + k0 + kv);
            As[kv + 0][m] = v.x;
            As[kv + 1][m] = v.y;
            As[kv + 2][m] = v.z;
            As[kv + 3][m] = v.w;
        }
        #pragma unroll
        for (int p = 0; p < 4; ++p) {
            int k  = p * 8 + (t >> 5);
            int nv = (t & 31) << 2;
            *reinterpret_cast<float4*>(&Bs[k][nv]) =
                *reinterpret_cast<const float4*>(Wt + (size_t)(k0 + k) * BN + nv);
        }
        __syncthreads();

        #pragma unroll
        for (int k = 0; k < BK; ++k) {
            float4 a0 = *reinterpret_cast<const float4*>(&As[k][trow]);
            float4 a1 = *reinterpret_cast<const float4*>(&As[k][trow + 4]);
            float4 b0 = *reinterpret_cast<const float4*>(&Bs[k][tcol]);
            float4 b1 = *reinterpret_cast<const float4*>(&Bs[k][tcol + 4]);
            float a[8] = {a0.x, a0.y, a0.z, a0.w, a1.x, a1.y, a1.z, a1.w};
            float bb[8] = {b0.x, b0.y, b0.z, b0.w, b1.x, b1.y, b1.z, b1.w};
            #pragma unroll
            for (int i = 0; i < 8; ++i)
                #pragma unroll
                for (int j = 0; j < 8; ++j)
                    acc[i][j] += a[i] * bb[j];
        }
        __syncthreads();
    }

    #pragma unroll
    for (int i = 0; i < 8; ++i) {
        int gm = m_base + trow + i;
        if (gm >= M) continue;
        #pragma unroll
        for (int j = 0; j < 8; j += 4) {
            float4 r;
            r.x = acc[i][j + 0] + bias[tcol + j + 0];
            r.y = acc[i][j + 1] + bias[tcol + j + 1];
            r.z = acc[i][j + 2] + bias[tcol + j + 2];
            r.w = acc[i][j + 3] + bias[tcol + j + 3];
            *reinterpret_cast<float4*>(out + (size_t)gm * BN + tcol + j) = r;
        }
    }
}

extern "C" void kernel_launch(void* const* d_in, const int* in_sizes, int n_in,
                              void* d_out, int out_size, void* d_ws, size_t ws_size,
                              hipStream_t stream) {
    const float* src   = (const float*)d_in[0];
    const int*   index = (const int*)d_in[1];
    const float* W     = (const float*)d_in[2];
    const float* bias  = (const float*)d_in[3];

    const int n_edges = in_sizes[1];            // 1,600,000
    const int M       = out_size / D_FEAT;      // 50,000 (dim_size)

    // workspace layout
    float* A      = (float*)d_ws;                     // M * 256 f32
    float* Wt     = A + (size_t)M * 2 * D_FEAT;       // 256*128 f32
    int*   cnt    = (int*)(Wt + 2 * D_FEAT * D_FEAT); // M
    int*   off    = cnt + M;                          // M + 1
    int*   cursor = off + M + 1;                      // M
    int*   order  = cursor + M;                       // n_edges
    int*   bsum   = order + n_edges;                  // <= 64
    int*   boff   = bsum + 64;                        // <= 64

    const int nblk = (M + SCAN_ITEMS - 1) / SCAN_ITEMS;   // 25 for M=50000

    setup_kernel<<<(max(M, 2 * D_FEAT * D_FEAT) + 255) / 256, 256, 0, stream>>>(W, Wt, cnt, M);

    int n4 = n_edges / 4;
    int eb4 = (max(n4, n_edges - 4 * n4) + 255) / 256;
    hist_kernel<<<eb4, 256, 0, stream>>>(index, cnt, n4, n_edges);

    blocksum_kernel<<<nblk, 256, 0, stream>>>(cnt, bsum, M);
    scanblk_kernel<<<1, 64, 0, stream>>>(bsum, boff, off, M, nblk);
    apply_kernel<<<nblk, 256, 0, stream>>>(cnt, boff, off, cursor, M);

    order_kernel<<<eb4, 256, 0, stream>>>(index, cursor, order, n4, n_edges);

    int rb = (M * 64 + 255) / 256;
    reduce_kernel<<<rb, 256, 0, stream>>>(src, order, off, A, M);

    gemm_kernel<<<(M + BM - 1) / BM, 256, 0, stream>>>(A, Wt, bias, (float*)d_out, M);
}